// Round 1
// baseline (1128.616 us; speedup 1.0000x reference)
//
#include <hip/hip_runtime.h>
#include <math.h>

#define SS   1024   // sequence length
#define DM   1024   // d_model
#define NH   16     // heads
#define DKH  64     // head dim
#define NB   4      // batch
#define NBH  64     // B*H

__device__ __forceinline__ float rsum16(float v){
  v += __shfl_xor(v, 1, 64);
  v += __shfl_xor(v, 2, 64);
  v += __shfl_xor(v, 4, 64);
  v += __shfl_xor(v, 8, 64);
  return v;
}
__device__ __forceinline__ float rmax16(float v){
  v = fmaxf(v, __shfl_xor(v, 1, 64));
  v = fmaxf(v, __shfl_xor(v, 2, 64));
  v = fmaxf(v, __shfl_xor(v, 4, 64));
  v = fmaxf(v, __shfl_xor(v, 8, 64));
  return v;
}

// out = A(MxK) @ W(KxN) + bias
// mode 0: row-major (M,N) output; mode 1: scatter to (B,H,S,dk) layout
__global__ __launch_bounds__(256) void gemm_bias128(
    const float* __restrict__ A, const float* __restrict__ W,
    const float* __restrict__ bias, float* __restrict__ out,
    int M, int K, int N, int mode)
{
  __shared__ float Ast[16][132];
  __shared__ float Bst[16][132];
  const int tid = threadIdx.x;
  const int tx = tid & 15, ty = tid >> 4;
  const int m0 = blockIdx.y * 128, n0 = blockIdx.x * 128;

  float acc[2][2][4][4];
  #pragma unroll
  for (int a = 0; a < 2; ++a)
    #pragma unroll
    for (int b = 0; b < 2; ++b)
      #pragma unroll
      for (int i = 0; i < 4; ++i)
        #pragma unroll
        for (int j = 0; j < 4; ++j) acc[a][b][i][j] = 0.f;

  for (int kt = 0; kt < K; kt += 16){
    __syncthreads();
    #pragma unroll
    for (int it = 0; it < 2; ++it){
      int idx = tid + it*256;
      int r = idx >> 2, kg = (idx & 3) << 2;
      const float4 v = *(const float4*)&A[(size_t)(m0+r)*K + kt + kg];
      Ast[kg+0][r] = v.x; Ast[kg+1][r] = v.y; Ast[kg+2][r] = v.z; Ast[kg+3][r] = v.w;
    }
    #pragma unroll
    for (int it = 0; it < 2; ++it){
      int idx = tid + it*256;
      int kr = idx >> 5, ng = (idx & 31) << 2;
      *(float4*)&Bst[kr][ng] = *(const float4*)&W[(size_t)(kt+kr)*N + n0 + ng];
    }
    __syncthreads();
    #pragma unroll
    for (int k = 0; k < 16; ++k){
      float a0[4], a1[4], b0[4], b1[4];
      *(float4*)a0 = *(const float4*)&Ast[k][4*ty];
      *(float4*)a1 = *(const float4*)&Ast[k][64 + 4*ty];
      *(float4*)b0 = *(const float4*)&Bst[k][4*tx];
      *(float4*)b1 = *(const float4*)&Bst[k][64 + 4*tx];
      #pragma unroll
      for (int i = 0; i < 4; ++i){
        #pragma unroll
        for (int j = 0; j < 4; ++j){
          acc[0][0][i][j] = fmaf(a0[i], b0[j], acc[0][0][i][j]);
          acc[0][1][i][j] = fmaf(a0[i], b1[j], acc[0][1][i][j]);
          acc[1][0][i][j] = fmaf(a1[i], b0[j], acc[1][0][i][j]);
          acc[1][1][i][j] = fmaf(a1[i], b1[j], acc[1][1][i][j]);
        }
      }
    }
  }

  float bb0[4], bb1[4];
  *(float4*)bb0 = *(const float4*)&bias[n0 + 4*tx];
  *(float4*)bb1 = *(const float4*)&bias[n0 + 64 + 4*tx];
  #pragma unroll
  for (int rg = 0; rg < 2; ++rg){
    #pragma unroll
    for (int i = 0; i < 4; ++i){
      int row = m0 + rg*64 + 4*ty + i;
      #pragma unroll
      for (int cg = 0; cg < 2; ++cg){
        const float* bb = cg ? bb1 : bb0;
        float4 o;
        o.x = acc[rg][cg][i][0] + bb[0];
        o.y = acc[rg][cg][i][1] + bb[1];
        o.z = acc[rg][cg][i][2] + bb[2];
        o.w = acc[rg][cg][i][3] + bb[3];
        if (mode == 0){
          *(float4*)&out[(size_t)row*N + n0 + cg*64 + 4*tx] = o;
        } else {
          int bidx = row >> 10, s = row & 1023;
          int h = (n0 >> 6) + cg;
          *(float4*)&out[(((size_t)(bidx*NH + h))*SS + s)*DKH + 4*tx] = o;
        }
      }
    }
  }
}

// Pass 1: per-(b,h) stats of s = clip(QK^T/8, +-50):
//   stats[bh*4+0] = sum s ; +1 = sum rowmax ; +2 = sum rowvar(softmax(s/2))
__global__ __launch_bounds__(256) void attn_stats(
    const float* __restrict__ Qw, const float* __restrict__ Kw,
    float* __restrict__ stats)
{
  __shared__ float Qt[64][68];
  __shared__ float Kt[64][68];
  __shared__ float red[3][16];
  const int tid = threadIdx.x, tx = tid & 15, ty = tid >> 4;
  const int bh = blockIdx.y, q0 = blockIdx.x * 64;
  const float* Qb = Qw + ((size_t)bh*SS + q0)*DKH;
  const float* Kb = Kw + (size_t)bh*SS*DKH;

  #pragma unroll
  for (int it = 0; it < 4; ++it){
    int idx = tid + it*256;
    int row = idx >> 4, dg = (idx & 15) << 2;
    const float4 v = *(const float4*)&Qb[(size_t)row*DKH + dg];
    Qt[dg+0][row] = v.x; Qt[dg+1][row] = v.y; Qt[dg+2][row] = v.z; Qt[dg+3][row] = v.w;
  }

  float rs_sum[4], rs_max[4], rs_l[4], rs_l2[4];
  #pragma unroll
  for (int i = 0; i < 4; ++i){ rs_sum[i]=0.f; rs_max[i]=-1e30f; rs_l[i]=0.f; rs_l2[i]=0.f; }

  for (int kc = 0; kc < 16; ++kc){
    __syncthreads();
    #pragma unroll
    for (int it = 0; it < 4; ++it){
      int idx = tid + it*256;
      int row = idx >> 4, dg = (idx & 15) << 2;
      const float4 v = *(const float4*)&Kb[(size_t)(kc*64+row)*DKH + dg];
      Kt[dg+0][row] = v.x; Kt[dg+1][row] = v.y; Kt[dg+2][row] = v.z; Kt[dg+3][row] = v.w;
    }
    __syncthreads();

    float s[4][4];
    #pragma unroll
    for (int i = 0; i < 4; ++i)
      #pragma unroll
      for (int j = 0; j < 4; ++j) s[i][j] = 0.f;
    #pragma unroll 16
    for (int d = 0; d < 64; ++d){
      float qa[4], kb[4];
      *(float4*)qa = *(const float4*)&Qt[d][4*ty];
      *(float4*)kb = *(const float4*)&Kt[d][4*tx];
      #pragma unroll
      for (int i = 0; i < 4; ++i)
        #pragma unroll
        for (int j = 0; j < 4; ++j) s[i][j] = fmaf(qa[i], kb[j], s[i][j]);
    }
    #pragma unroll
    for (int i = 0; i < 4; ++i)
      #pragma unroll
      for (int j = 0; j < 4; ++j)
        s[i][j] = fminf(fmaxf(s[i][j]*0.125f, -50.f), 50.f);

    #pragma unroll
    for (int i = 0; i < 4; ++i){
      float cs = s[i][0]+s[i][1]+s[i][2]+s[i][3];
      float cm = fmaxf(fmaxf(s[i][0],s[i][1]), fmaxf(s[i][2],s[i][3]));
      cs = rsum16(cs); cm = rmax16(cm);
      rs_sum[i] += cs;
      float mo = rs_max[i]*0.5f;
      rs_max[i] = fmaxf(rs_max[i], cm);
      float mn = rs_max[i]*0.5f;
      float el = 0.f, el2 = 0.f;
      #pragma unroll
      for (int j = 0; j < 4; ++j){
        float e = __expf(s[i][j]*0.5f - mn);
        el += e; el2 += e*e;
      }
      el = rsum16(el); el2 = rsum16(el2);
      float al = __expf(mo - mn);
      rs_l[i]  = rs_l[i]*al + el;
      rs_l2[i] = rs_l2[i]*(al*al) + el2;
    }
  }

  float vs = 0.f, vm = 0.f, vv = 0.f;
  if (tx == 0){
    #pragma unroll
    for (int i = 0; i < 4; ++i){
      vs += rs_sum[i];
      vm += rs_max[i];
      float sp2 = rs_l2[i] / (rs_l[i]*rs_l[i]);      // sum p^2
      vv += (sp2 - (1.0f/1024.f)) * (1.0f/1023.f);   // unbiased var
    }
  }
  __syncthreads();
  if (tx == 0){ red[0][ty] = vs; red[1][ty] = vm; red[2][ty] = vv; }
  __syncthreads();
  if (tid == 0){
    float a0=0.f,a1=0.f,a2=0.f;
    for (int t = 0; t < 16; ++t){ a0+=red[0][t]; a1+=red[1][t]; a2+=red[2][t]; }
    atomicAdd(&stats[bh*4+0], a0);
    atomicAdd(&stats[bh*4+1], a1);
    atomicAdd(&stats[bh*4+2], a2);
  }
}

__global__ void time_mlp(const float* __restrict__ stats,
    const float* __restrict__ Wt1, const float* __restrict__ bt1,
    const float* __restrict__ Wt2, const float* __restrict__ bt2,
    float* __restrict__ tws)
{
  int bh = threadIdx.x;
  if (bh >= NBH) return;
  float mean = stats[bh*4+0] * (1.f/(1024.f*1024.f));
  float mx   = stats[bh*4+1] * (1.f/1024.f);
  float ent  = stats[bh*4+2] * (1.f/1024.f);
  mean = fminf(fmaxf(mean, -10.f), 10.f);
  mx   = fminf(fmaxf(mx,   -10.f), 10.f);
  ent  = fminf(fmaxf(ent,    0.f),  1.f);
  float raw = bt2[0];
  #pragma unroll
  for (int j = 0; j < 16; ++j){
    float h = tanhf(mean*Wt1[j] + mx*Wt1[16+j] + ent*Wt1[32+j] + bt1[j]);
    raw += h * Wt2[j];
  }
  float sig = 1.f / (1.f + expf(-raw));
  float t = 0.01f + sig * 1.99f;
  t = fminf(fmaxf(t, 0.01f), 2.0f);
  t = fminf(t, 0.85f);
  tws[bh] = t;
}

// Pass 2: flash attention, scores = QK^T / (2t), output to (B,S,D) layout
__global__ __launch_bounds__(256) void attn_flash(
    const float* __restrict__ Qw, const float* __restrict__ Kw,
    const float* __restrict__ Vw, const float* __restrict__ tws,
    float* __restrict__ outw)
{
  __shared__ float Qt[64][68];
  __shared__ float KtPs[64][68];  // K^T during QK phase, then P
  __shared__ float Vs[64][64];
  const int tid = threadIdx.x, tx = tid & 15, ty = tid >> 4;
  const int bh = blockIdx.y, q0 = blockIdx.x * 64;
  const float* Qb = Qw + ((size_t)bh*SS + q0)*DKH;
  const float* Kb = Kw + (size_t)bh*SS*DKH;
  const float* Vb = Vw + (size_t)bh*SS*DKH;
  const float tsc = 0.5f / tws[bh];

  #pragma unroll
  for (int it = 0; it < 4; ++it){
    int idx = tid + it*256;
    int row = idx >> 4, dg = (idx & 15) << 2;
    const float4 v = *(const float4*)&Qb[(size_t)row*DKH + dg];
    Qt[dg+0][row] = v.x; Qt[dg+1][row] = v.y; Qt[dg+2][row] = v.z; Qt[dg+3][row] = v.w;
  }

  float o[4][4];
  float mrun[4], lrun[4];
  #pragma unroll
  for (int i = 0; i < 4; ++i){
    mrun[i] = -1e30f; lrun[i] = 0.f;
    #pragma unroll
    for (int j = 0; j < 4; ++j) o[i][j] = 0.f;
  }

  for (int kc = 0; kc < 16; ++kc){
    __syncthreads();   // previous PV done (KtPs, Vs free)
    #pragma unroll
    for (int it = 0; it < 4; ++it){
      int idx = tid + it*256;
      int row = idx >> 4, dg = (idx & 15) << 2;
      const float4 kv = *(const float4*)&Kb[(size_t)(kc*64+row)*DKH + dg];
      KtPs[dg+0][row] = kv.x; KtPs[dg+1][row] = kv.y; KtPs[dg+2][row] = kv.z; KtPs[dg+3][row] = kv.w;
      const float4 vv = *(const float4*)&Vb[(size_t)(kc*64+row)*DKH + dg];
      *(float4*)&Vs[row][dg] = vv;
    }
    __syncthreads();

    float s[4][4];
    #pragma unroll
    for (int i = 0; i < 4; ++i)
      #pragma unroll
      for (int j = 0; j < 4; ++j) s[i][j] = 0.f;
    #pragma unroll 16
    for (int d = 0; d < 64; ++d){
      float qa[4], kb[4];
      *(float4*)qa = *(const float4*)&Qt[d][4*ty];
      *(float4*)kb = *(const float4*)&KtPs[d][4*tx];
      #pragma unroll
      for (int i = 0; i < 4; ++i)
        #pragma unroll
        for (int j = 0; j < 4; ++j) s[i][j] = fmaf(qa[i], kb[j], s[i][j]);
    }
    #pragma unroll
    for (int i = 0; i < 4; ++i)
      #pragma unroll
      for (int j = 0; j < 4; ++j) s[i][j] *= tsc;

    __syncthreads();   // all threads done reading K^T

    #pragma unroll
    for (int i = 0; i < 4; ++i){
      float cm = fmaxf(fmaxf(s[i][0],s[i][1]), fmaxf(s[i][2],s[i][3]));
      cm = rmax16(cm);
      float mn = fmaxf(mrun[i], cm);
      float al = __expf(mrun[i] - mn);
      mrun[i] = mn;
      float ls = 0.f;
      #pragma unroll
      for (int j = 0; j < 4; ++j){ s[i][j] = __expf(s[i][j] - mn); ls += s[i][j]; }
      ls = rsum16(ls);
      lrun[i] = lrun[i]*al + ls;
      #pragma unroll
      for (int j = 0; j < 4; ++j) o[i][j] *= al;
      KtPs[4*ty+i][4*tx+0] = s[i][0];
      KtPs[4*ty+i][4*tx+1] = s[i][1];
      KtPs[4*ty+i][4*tx+2] = s[i][2];
      KtPs[4*ty+i][4*tx+3] = s[i][3];
    }
    __syncthreads();   // P visible

    #pragma unroll 8
    for (int kk = 0; kk < 64; ++kk){
      float vv[4];
      *(float4*)vv = *(const float4*)&Vs[kk][4*tx];
      #pragma unroll
      for (int i = 0; i < 4; ++i){
        float pr = KtPs[4*ty+i][kk];
        #pragma unroll
        for (int j = 0; j < 4; ++j) o[i][j] = fmaf(pr, vv[j], o[i][j]);
      }
    }
  }

  const int b = bh >> 4, h = bh & 15;
  #pragma unroll
  for (int i = 0; i < 4; ++i){
    float inv = 1.f / lrun[i];
    float4 ov;
    ov.x = o[i][0]*inv; ov.y = o[i][1]*inv; ov.z = o[i][2]*inv; ov.w = o[i][3]*inv;
    *(float4*)&outw[((size_t)(b*SS + q0 + 4*ty + i))*DM + h*DKH + 4*tx] = ov;
  }
}

extern "C" void kernel_launch(void* const* d_in, const int* in_sizes, int n_in,
                              void* d_out, int out_size, void* d_ws, size_t ws_size,
                              hipStream_t stream)
{
  const float* query = (const float*)d_in[0];
  const float* key   = (const float*)d_in[1];
  const float* value = (const float*)d_in[2];
  const float* Wq = (const float*)d_in[3];
  const float* bq = (const float*)d_in[4];
  const float* Wk = (const float*)d_in[5];
  const float* bk = (const float*)d_in[6];
  const float* Wv = (const float*)d_in[7];
  const float* bv = (const float*)d_in[8];
  const float* Wo = (const float*)d_in[9];
  const float* bo = (const float*)d_in[10];
  const float* Wt1 = (const float*)d_in[11];
  const float* bt1 = (const float*)d_in[12];
  const float* Wt2 = (const float*)d_in[13];
  const float* bt2 = (const float*)d_in[14];
  float* out = (float*)d_out;

  float* ws = (float*)d_ws;
  const size_t PROJ = (size_t)NB*SS*DM;   // 4,194,304 floats
  float* qws   = ws;
  float* kws   = qws + PROJ;
  float* vws   = kws + PROJ;
  float* aws   = vws + PROJ;
  float* stats = aws + PROJ;
  float* tws   = stats + 4*NBH;

  hipMemsetAsync(stats, 0, 4*NBH*sizeof(float), stream);

  dim3 gg(DM/128, (NB*SS)/128);   // (8, 32)
  gemm_bias128<<<gg, 256, 0, stream>>>(query, Wq, bq, qws, NB*SS, DM, DM, 1);
  gemm_bias128<<<gg, 256, 0, stream>>>(key,   Wk, bk, kws, NB*SS, DM, DM, 1);
  gemm_bias128<<<gg, 256, 0, stream>>>(value, Wv, bv, vws, NB*SS, DM, DM, 1);

  dim3 ga(SS/64, NBH);            // (16, 64)
  attn_stats<<<ga, 256, 0, stream>>>(qws, kws, stats);
  time_mlp<<<1, 64, 0, stream>>>(stats, Wt1, bt1, Wt2, bt2, tws);
  attn_flash<<<ga, 256, 0, stream>>>(qws, kws, vws, tws, aws);

  gemm_bias128<<<gg, 256, 0, stream>>>(aws, Wo, bo, out, NB*SS, DM, DM, 0);
}

// Round 2
// 350.672 us; speedup vs baseline: 3.2184x; 3.2184x over previous
//
#include <hip/hip_runtime.h>
#include <math.h>

#define SS   1024
#define DM   1024
#define NH   16
#define DKH  64
#define NB   4
#define NBH  64

typedef __attribute__((ext_vector_type(8))) short bf8_t;   // 8 bf16 = 4 VGPR
typedef __attribute__((ext_vector_type(4))) float f32x4;
#define MFMA16(a,b,c) __builtin_amdgcn_mfma_f32_16x16x32_bf16((a),(b),(c),0,0,0)

__device__ __forceinline__ unsigned short f2bf(float x){
  unsigned int u = __float_as_uint(x);
  return (unsigned short)((u + 0x7FFFu + ((u >> 16) & 1u)) >> 16);
}
__device__ __forceinline__ float bf2f(unsigned short h){
  return __uint_as_float(((unsigned int)h) << 16);
}
__device__ __forceinline__ float rsum16(float v){
  v += __shfl_xor(v, 1, 64);
  v += __shfl_xor(v, 2, 64);
  v += __shfl_xor(v, 4, 64);
  v += __shfl_xor(v, 8, 64);
  return v;
}
__device__ __forceinline__ float rmax16(float v){
  v = fmaxf(v, __shfl_xor(v, 1, 64));
  v = fmaxf(v, __shfl_xor(v, 2, 64));
  v = fmaxf(v, __shfl_xor(v, 4, 64));
  v = fmaxf(v, __shfl_xor(v, 8, 64));
  return v;
}

// Weight convert: W (K=1024 x N=1024) fp32 -> Wt (N x K) bf16 hi (+ lo if dosplit)
__global__ void wconv(const float* __restrict__ W,
                      unsigned short* __restrict__ Th,
                      unsigned short* __restrict__ Tl, int dosplit)
{
  __shared__ float T[32][33];
  const int tx = threadIdx.x, ty = threadIdx.y;   // (32,8)
  const int k0 = blockIdx.y * 32, n0 = blockIdx.x * 32;
  #pragma unroll
  for (int i = 0; i < 4; ++i){
    int r = ty + 8*i;
    T[r][tx] = W[(size_t)(k0 + r)*DM + n0 + tx];
  }
  __syncthreads();
  #pragma unroll
  for (int i = 0; i < 4; ++i){
    int r = ty + 8*i;              // n-local
    float v = T[tx][r];            // [k-local][n-local]
    unsigned short hh = f2bf(v);
    Th[(size_t)(n0 + r)*DM + k0 + tx] = hh;
    if (dosplit) Tl[(size_t)(n0 + r)*DM + k0 + tx] = f2bf(v - bf2f(hh));
  }
}

// MFMA GEMM: C = A(4096x1024) @ Wt^T + bias, Wt stored (N,K) bf16.
// AMODE 0: A fp32, split hi/lo on the fly, 3-term MFMA (fp32-grade)
// AMODE 1: A fp32 -> plain bf16
// AMODE 2: A already bf16
// OUTMODE 0: fp32 (M,N) + bias      (final output)
// OUTMODE 1: split bf16 scatter to (b*16+h, s, dk)  (Q,K)
// OUTMODE 2: bf16 transposed to (b*16+h, dk, s)     (V)
template<int AMODE, int OUTMODE>
__global__ __launch_bounds__(256) void gemm_mfma(
    const float* __restrict__ Af, const unsigned short* __restrict__ Abf,
    const unsigned short* __restrict__ Bth, const unsigned short* __restrict__ Btl,
    const float* __restrict__ bias,
    float* __restrict__ outf, unsigned short* __restrict__ outh,
    unsigned short* __restrict__ outl)
{
  constexpr int LDT = 40;          // bf16 stride: 80B rows, 16B-aligned, ~2-way banks
  constexpr bool SPLIT = (AMODE == 0);
  extern __shared__ unsigned short sm[];
  unsigned short* As_h = sm;
  unsigned short* Bs_h = sm + 128*LDT;
  unsigned short* As_l = sm + 2*128*LDT;
  unsigned short* Bs_l = sm + 3*128*LDT;

  const int tid = threadIdx.x;
  const int lane = tid & 63, w = tid >> 6;
  const int c = lane & 15, g = lane >> 4;
  const int wr = w >> 1, wc = w & 1;
  const int m0 = blockIdx.y * 128, n0 = blockIdx.x * 128;

  f32x4 acc[4][4];
  #pragma unroll
  for (int i = 0; i < 4; ++i)
    #pragma unroll
    for (int j = 0; j < 4; ++j) acc[i][j] = (f32x4){0.f,0.f,0.f,0.f};

  const int sr = tid >> 1;              // staging row 0..127
  const int sk = (tid & 1) * 16;        // staging k-half

  for (int kt = 0; kt < DM; kt += 32){
    __syncthreads();
    // ---- stage A
    if (AMODE == 2){
      const unsigned short* ap = Abf + (size_t)(m0 + sr)*DM + kt + sk;
      *(uint4*)&As_h[sr*LDT + sk]     = *(const uint4*)(ap);
      *(uint4*)&As_h[sr*LDT + sk + 8] = *(const uint4*)(ap + 8);
    } else {
      const float* ap = Af + (size_t)(m0 + sr)*DM + kt + sk;
      float av[16];
      *(float4*)&av[0]  = *(const float4*)(ap);
      *(float4*)&av[4]  = *(const float4*)(ap + 4);
      *(float4*)&av[8]  = *(const float4*)(ap + 8);
      *(float4*)&av[12] = *(const float4*)(ap + 12);
      unsigned short hv[16];
      #pragma unroll
      for (int i = 0; i < 16; ++i) hv[i] = f2bf(av[i]);
      *(uint4*)&As_h[sr*LDT + sk]     = *(const uint4*)&hv[0];
      *(uint4*)&As_h[sr*LDT + sk + 8] = *(const uint4*)&hv[8];
      if (SPLIT){
        unsigned short lv[16];
        #pragma unroll
        for (int i = 0; i < 16; ++i) lv[i] = f2bf(av[i] - bf2f(hv[i]));
        *(uint4*)&As_l[sr*LDT + sk]     = *(const uint4*)&lv[0];
        *(uint4*)&As_l[sr*LDT + sk + 8] = *(const uint4*)&lv[8];
      }
    }
    // ---- stage B (pre-transposed bf16 weights)
    {
      const unsigned short* bp = Bth + (size_t)(n0 + sr)*DM + kt + sk;
      *(uint4*)&Bs_h[sr*LDT + sk]     = *(const uint4*)(bp);
      *(uint4*)&Bs_h[sr*LDT + sk + 8] = *(const uint4*)(bp + 8);
      if (SPLIT){
        const unsigned short* blp = Btl + (size_t)(n0 + sr)*DM + kt + sk;
        *(uint4*)&Bs_l[sr*LDT + sk]     = *(const uint4*)(blp);
        *(uint4*)&Bs_l[sr*LDT + sk + 8] = *(const uint4*)(blp + 8);
      }
    }
    __syncthreads();

    bf8_t a_h[4], a_l[4];
    #pragma unroll
    for (int fm = 0; fm < 4; ++fm){
      a_h[fm] = *(const bf8_t*)&As_h[(64*wr + 16*fm + c)*LDT + 8*g];
      if (SPLIT) a_l[fm] = *(const bf8_t*)&As_l[(64*wr + 16*fm + c)*LDT + 8*g];
    }
    #pragma unroll
    for (int fn = 0; fn < 4; ++fn){
      bf8_t b_h = *(const bf8_t*)&Bs_h[(64*wc + 16*fn + c)*LDT + 8*g];
      if (SPLIT){
        bf8_t b_l = *(const bf8_t*)&Bs_l[(64*wc + 16*fn + c)*LDT + 8*g];
        #pragma unroll
        for (int fm = 0; fm < 4; ++fm){
          acc[fm][fn] = MFMA16(a_h[fm], b_h, acc[fm][fn]);
          acc[fm][fn] = MFMA16(a_h[fm], b_l, acc[fm][fn]);
          acc[fm][fn] = MFMA16(a_l[fm], b_h, acc[fm][fn]);
        }
      } else {
        #pragma unroll
        for (int fm = 0; fm < 4; ++fm)
          acc[fm][fn] = MFMA16(a_h[fm], b_h, acc[fm][fn]);
      }
    }
  }

  // ---- epilogue (C/D layout: col = lane&15, row = 4*(lane>>4)+reg)
  #pragma unroll
  for (int fm = 0; fm < 4; ++fm){
    #pragma unroll
    for (int fn = 0; fn < 4; ++fn){
      const int col = n0 + 64*wc + 16*fn + c;
      const float bb = bias[col];
      const int row0 = m0 + 64*wr + 16*fm + 4*g;
      if (OUTMODE == 0){
        #pragma unroll
        for (int r = 0; r < 4; ++r)
          outf[(size_t)(row0 + r)*DM + col] = acc[fm][fn][r] + bb;
      } else if (OUTMODE == 1){
        const int hd = col >> 6, d = col & 63;
        #pragma unroll
        for (int r = 0; r < 4; ++r){
          const int row = row0 + r;
          const int b = row >> 10, s = row & 1023;
          const size_t a = ((size_t)(b*NH + hd)*SS + s)*DKH + d;
          float v = acc[fm][fn][r] + bb;
          unsigned short hh = f2bf(v);
          outh[a] = hh;
          outl[a] = f2bf(v - bf2f(hh));
        }
      } else {
        const int hd = col >> 6, d = col & 63;
        const int b = row0 >> 10, s = row0 & 1023;
        const size_t a = ((size_t)(b*NH + hd)*DKH + d)*SS + s;
        unsigned short h0 = f2bf(acc[fm][fn][0] + bb);
        unsigned short h1 = f2bf(acc[fm][fn][1] + bb);
        unsigned short h2 = f2bf(acc[fm][fn][2] + bb);
        unsigned short h3 = f2bf(acc[fm][fn][3] + bb);
        uint2 pk;
        pk.x = (unsigned int)h0 | ((unsigned int)h1 << 16);
        pk.y = (unsigned int)h2 | ((unsigned int)h3 << 16);
        *(uint2*)&outh[a] = pk;
      }
    }
  }
}

// Stats pass: s = clip(QK^T/8, +-50); accumulate sum(s), sum(rowmax), sum(rowvar(softmax(s/2)))
__global__ __launch_bounds__(256) void attn_stats_mfma(
    const unsigned short* __restrict__ Qh, const unsigned short* __restrict__ Ql,
    const unsigned short* __restrict__ Kh, const unsigned short* __restrict__ Kl,
    float* __restrict__ stats)
{
  __shared__ unsigned short Khs[64*72], Kls[64*72];
  __shared__ float red[3][4];
  const int tid = threadIdx.x, lane = tid & 63, w = tid >> 6;
  const int c = lane & 15, g = lane >> 4;
  const int bh = blockIdx.y, q0 = blockIdx.x * 64;

  bf8_t qh[2], ql[2];
  {
    const size_t qoff = ((size_t)bh*SS + q0 + 16*w + c)*DKH + 8*g;
    qh[0] = *(const bf8_t*)(Qh + qoff);  qh[1] = *(const bf8_t*)(Qh + qoff + 32);
    ql[0] = *(const bf8_t*)(Ql + qoff);  ql[1] = *(const bf8_t*)(Ql + qoff + 32);
  }

  float mrow[4], lrow[4], l2row[4], ssum = 0.f;
  #pragma unroll
  for (int r = 0; r < 4; ++r){ mrow[r] = -1e30f; lrow[r] = 0.f; l2row[r] = 0.f; }

  const int strow = tid >> 3, stch = (tid & 7) * 8;

  for (int kc = 0; kc < 16; ++kc){
    __syncthreads();
    #pragma unroll
    for (int rep = 0; rep < 2; ++rep){
      int rr = strow + 32*rep;
      const size_t go = ((size_t)bh*SS + kc*64 + rr)*DKH + stch;
      *(uint4*)&Khs[rr*72 + stch] = *(const uint4*)(Kh + go);
      *(uint4*)&Kls[rr*72 + stch] = *(const uint4*)(Kl + go);
    }
    __syncthreads();

    f32x4 sa[4];
    #pragma unroll
    for (int fn = 0; fn < 4; ++fn) sa[fn] = (f32x4){0.f,0.f,0.f,0.f};
    #pragma unroll
    for (int fn = 0; fn < 4; ++fn){
      #pragma unroll
      for (int ds = 0; ds < 2; ++ds){
        bf8_t kb_h = *(const bf8_t*)&Khs[(c + 16*fn)*72 + 8*g + 32*ds];
        bf8_t kb_l = *(const bf8_t*)&Kls[(c + 16*fn)*72 + 8*g + 32*ds];
        sa[fn] = MFMA16(qh[ds], kb_h, sa[fn]);
        sa[fn] = MFMA16(qh[ds], kb_l, sa[fn]);
        sa[fn] = MFMA16(ql[ds], kb_h, sa[fn]);
      }
    }
    #pragma unroll
    for (int r = 0; r < 4; ++r){
      float x[4];
      #pragma unroll
      for (int fn = 0; fn < 4; ++fn){
        float v = sa[fn][r] * 0.125f;
        x[fn] = fminf(fmaxf(v, -50.f), 50.f);
      }
      ssum += x[0] + x[1] + x[2] + x[3];
      float cm = fmaxf(fmaxf(x[0], x[1]), fmaxf(x[2], x[3]));
      cm = rmax16(cm);
      float mold = mrow[r];
      float mnew = fmaxf(mold, cm);
      mrow[r] = mnew;
      float mh = mnew * 0.5f;
      float e0 = __expf(x[0]*0.5f - mh), e1 = __expf(x[1]*0.5f - mh);
      float e2 = __expf(x[2]*0.5f - mh), e3 = __expf(x[3]*0.5f - mh);
      float el  = rsum16(e0 + e1 + e2 + e3);
      float el2 = rsum16(e0*e0 + e1*e1 + e2*e2 + e3*e3);
      float al = __expf(mold*0.5f - mh);
      lrow[r]  = lrow[r]*al + el;
      l2row[r] = l2row[r]*(al*al) + el2;
    }
  }

  float vm = 0.f, vv = 0.f;
  if (c == 0){
    #pragma unroll
    for (int r = 0; r < 4; ++r){
      vm += mrow[r];
      float sp2 = l2row[r] / (lrow[r]*lrow[r]);
      vv += (sp2 - (1.0f/1024.f)) * (1.0f/1023.f);
    }
  }
  #pragma unroll
  for (int off = 1; off < 64; off <<= 1){
    ssum += __shfl_xor(ssum, off, 64);
    vm   += __shfl_xor(vm, off, 64);
    vv   += __shfl_xor(vv, off, 64);
  }
  if (lane == 0){ red[0][w] = ssum; red[1][w] = vm; red[2][w] = vv; }
  __syncthreads();
  if (tid == 0){
    atomicAdd(&stats[bh*4+0], red[0][0]+red[0][1]+red[0][2]+red[0][3]);
    atomicAdd(&stats[bh*4+1], red[1][0]+red[1][1]+red[1][2]+red[1][3]);
    atomicAdd(&stats[bh*4+2], red[2][0]+red[2][1]+red[2][2]+red[2][3]);
  }
}

__global__ void time_mlp(const float* __restrict__ stats,
    const float* __restrict__ Wt1, const float* __restrict__ bt1,
    const float* __restrict__ Wt2, const float* __restrict__ bt2,
    float* __restrict__ tws)
{
  int bh = threadIdx.x;
  if (bh >= NBH) return;
  float mean = stats[bh*4+0] * (1.f/(1024.f*1024.f));
  float mx   = stats[bh*4+1] * (1.f/1024.f);
  float ent  = stats[bh*4+2] * (1.f/1024.f);
  mean = fminf(fmaxf(mean, -10.f), 10.f);
  mx   = fminf(fmaxf(mx,   -10.f), 10.f);
  ent  = fminf(fmaxf(ent,    0.f),  1.f);
  float raw = bt2[0];
  #pragma unroll
  for (int j = 0; j < 16; ++j){
    float h = tanhf(mean*Wt1[j] + mx*Wt1[16+j] + ent*Wt1[32+j] + bt1[j]);
    raw += h * Wt2[j];
  }
  float sig = 1.f / (1.f + expf(-raw));
  float t = 0.01f + sig * 1.99f;
  t = fminf(fmaxf(t, 0.01f), 2.0f);
  t = fminf(t, 0.85f);
  tws[bh] = t;
}

// Flash attention: scores = QK^T/(2t) (split MFMA), online softmax, PV via bf16 MFMA
__global__ __launch_bounds__(256) void attn_flash_mfma(
    const unsigned short* __restrict__ Qh, const unsigned short* __restrict__ Ql,
    const unsigned short* __restrict__ Kh, const unsigned short* __restrict__ Kl,
    const unsigned short* __restrict__ Vt, const float* __restrict__ tws,
    unsigned short* __restrict__ aout)
{
  __shared__ unsigned short Khs[64*72], Kls[64*72], Vts[64*72], Ps[64*72];
  const int tid = threadIdx.x, lane = tid & 63, w = tid >> 6;
  const int c = lane & 15, g = lane >> 4;
  const int bh = blockIdx.y, q0 = blockIdx.x * 64;
  const float tsc = 0.5f / tws[bh];

  bf8_t qh[2], ql[2];
  {
    const size_t qoff = ((size_t)bh*SS + q0 + 16*w + c)*DKH + 8*g;
    qh[0] = *(const bf8_t*)(Qh + qoff);  qh[1] = *(const bf8_t*)(Qh + qoff + 32);
    ql[0] = *(const bf8_t*)(Ql + qoff);  ql[1] = *(const bf8_t*)(Ql + qoff + 32);
  }

  f32x4 o[4];
  float mrow[4], lrow[4];
  #pragma unroll
  for (int i = 0; i < 4; ++i){ o[i] = (f32x4){0.f,0.f,0.f,0.f}; mrow[i] = -1e30f; lrow[i] = 0.f; }

  const int strow = tid >> 3, stch = (tid & 7) * 8;

  for (int kc = 0; kc < 16; ++kc){
    __syncthreads();
    #pragma unroll
    for (int rep = 0; rep < 2; ++rep){
      int rr = strow + 32*rep;
      const size_t go = ((size_t)bh*SS + kc*64 + rr)*DKH + stch;
      *(uint4*)&Khs[rr*72 + stch] = *(const uint4*)(Kh + go);
      *(uint4*)&Kls[rr*72 + stch] = *(const uint4*)(Kl + go);
      const size_t gv = ((size_t)bh*DKH + rr)*SS + kc*64 + stch;
      *(uint4*)&Vts[rr*72 + stch] = *(const uint4*)(Vt + gv);
    }
    __syncthreads();

    f32x4 sa[4];
    #pragma unroll
    for (int fn = 0; fn < 4; ++fn) sa[fn] = (f32x4){0.f,0.f,0.f,0.f};
    #pragma unroll
    for (int fn = 0; fn < 4; ++fn){
      #pragma unroll
      for (int ds = 0; ds < 2; ++ds){
        bf8_t kb_h = *(const bf8_t*)&Khs[(c + 16*fn)*72 + 8*g + 32*ds];
        bf8_t kb_l = *(const bf8_t*)&Kls[(c + 16*fn)*72 + 8*g + 32*ds];
        sa[fn] = MFMA16(qh[ds], kb_h, sa[fn]);
        sa[fn] = MFMA16(qh[ds], kb_l, sa[fn]);
        sa[fn] = MFMA16(ql[ds], kb_h, sa[fn]);
      }
    }
    // online softmax per row (rows live at reg r within lane-group g)
    #pragma unroll
    for (int r = 0; r < 4; ++r){
      float x[4];
      #pragma unroll
      for (int fn = 0; fn < 4; ++fn) x[fn] = sa[fn][r] * tsc;
      float cm = fmaxf(fmaxf(x[0], x[1]), fmaxf(x[2], x[3]));
      cm = rmax16(cm);
      float mnew = fmaxf(mrow[r], cm);
      float al = __expf(mrow[r] - mnew);
      mrow[r] = mnew;
      float e[4];
      #pragma unroll
      for (int fn = 0; fn < 4; ++fn) e[fn] = __expf(x[fn] - mnew);
      float ls = rsum16(e[0] + e[1] + e[2] + e[3]);
      lrow[r] = lrow[r]*al + ls;
      #pragma unroll
      for (int fn = 0; fn < 4; ++fn) o[fn][r] = o[fn][r] * al;
      const int prow = 16*w + 4*g + r;
      #pragma unroll
      for (int fn = 0; fn < 4; ++fn) Ps[prow*72 + 16*fn + c] = f2bf(e[fn]);
    }
    // PV: A = P (own rows, intra-wave), B = Vt tile
    #pragma unroll
    for (int kvs = 0; kvs < 2; ++kvs){
      bf8_t pa = *(const bf8_t*)&Ps[(16*w + c)*72 + 8*g + 32*kvs];
      #pragma unroll
      for (int fn = 0; fn < 4; ++fn){
        bf8_t vb = *(const bf8_t*)&Vts[(c + 16*fn)*72 + 8*g + 32*kvs];
        o[fn] = MFMA16(pa, vb, o[fn]);
      }
    }
  }

  const int b = bh >> 4, hd = bh & 15;
  #pragma unroll
  for (int fn = 0; fn < 4; ++fn){
    #pragma unroll
    for (int r = 0; r < 4; ++r){
      const int q = q0 + 16*w + 4*g + r;
      aout[((size_t)(b*SS + q))*DM + hd*DKH + 16*fn + c] = f2bf(o[fn][r] / lrow[r]);
    }
  }
}

extern "C" void kernel_launch(void* const* d_in, const int* in_sizes, int n_in,
                              void* d_out, int out_size, void* d_ws, size_t ws_size,
                              hipStream_t stream)
{
  const float* query = (const float*)d_in[0];
  const float* key   = (const float*)d_in[1];
  const float* value = (const float*)d_in[2];
  const float* Wq = (const float*)d_in[3];
  const float* bq = (const float*)d_in[4];
  const float* Wk = (const float*)d_in[5];
  const float* bk = (const float*)d_in[6];
  const float* Wv = (const float*)d_in[7];
  const float* bv = (const float*)d_in[8];
  const float* Wo = (const float*)d_in[9];
  const float* bo = (const float*)d_in[10];
  const float* Wt1 = (const float*)d_in[11];
  const float* bt1 = (const float*)d_in[12];
  const float* Wt2 = (const float*)d_in[13];
  const float* bt2 = (const float*)d_in[14];

  unsigned short* ws16 = (unsigned short*)d_ws;
  const size_t E = (size_t)NB*SS*DM;       // 4,194,304
  const size_t WE = (size_t)DM*DM;         // 1,048,576
  unsigned short* Qhb = ws16;
  unsigned short* Qlb = Qhb + E;
  unsigned short* Khb = Qlb + E;
  unsigned short* Klb = Khb + E;
  unsigned short* Vtb = Klb + E;
  unsigned short* Aob = Vtb + E;
  unsigned short* Wqh = Aob + E;
  unsigned short* Wql = Wqh + WE;
  unsigned short* Wkh = Wql + WE;
  unsigned short* Wkl = Wkh + WE;
  unsigned short* Wvh = Wkl + WE;
  unsigned short* Woh = Wvh + WE;
  float* stats = (float*)(Woh + WE);
  float* tws   = stats + 4*NBH;

  hipMemsetAsync(stats, 0, 4*NBH*sizeof(float), stream);

  dim3 wb(32, 8), wg(32, 32);
  wconv<<<wg, wb, 0, stream>>>(Wq, Wqh, Wql, 1);
  wconv<<<wg, wb, 0, stream>>>(Wk, Wkh, Wkl, 1);
  wconv<<<wg, wb, 0, stream>>>(Wv, Wvh, nullptr, 0);
  wconv<<<wg, wb, 0, stream>>>(Wo, Woh, nullptr, 0);

  dim3 gg(DM/128, (NB*SS)/128);            // (8, 32)
  const size_t shm_split = 4u*128*40*2;    // 40960 B
  const size_t shm_plain = 2u*128*40*2;    // 20480 B
  gemm_mfma<0,1><<<gg, 256, shm_split, stream>>>(query, nullptr, Wqh, Wql, bq, nullptr, Qhb, Qlb);
  gemm_mfma<0,1><<<gg, 256, shm_split, stream>>>(key,   nullptr, Wkh, Wkl, bk, nullptr, Khb, Klb);
  gemm_mfma<1,2><<<gg, 256, shm_plain, stream>>>(value, nullptr, Wvh, nullptr, bv, nullptr, Vtb, nullptr);

  dim3 ga(SS/64, NBH);                     // (16, 64)
  attn_stats_mfma<<<ga, 256, 0, stream>>>(Qhb, Qlb, Khb, Klb, stats);
  time_mlp<<<1, 64, 0, stream>>>(stats, Wt1, bt1, Wt2, bt2, tws);
  attn_flash_mfma<<<ga, 256, 0, stream>>>(Qhb, Qlb, Khb, Klb, Vtb, tws, Aob);

  gemm_mfma<2,0><<<gg, 256, shm_plain, stream>>>(nullptr, Aob, Woh, nullptr, bo, (float*)d_out, nullptr, nullptr);
}

// Round 3
// 294.923 us; speedup vs baseline: 3.8268x; 1.1890x over previous
//
#include <hip/hip_runtime.h>
#include <hip/hip_bf16.h>
#include <math.h>

#define SS   1024
#define DM   1024
#define NH   16
#define DKH  64
#define NB   4
#define NBH  64

typedef unsigned short ush;
typedef __attribute__((ext_vector_type(8))) short bf8_t;   // 8 bf16 = 4 VGPR
typedef __attribute__((ext_vector_type(4))) float f32x4;
#define MFMA16(a,b,c) __builtin_amdgcn_mfma_f32_16x16x32_bf16((a),(b),(c),0,0,0)

__device__ __forceinline__ ush f2bf(float x){
  return __bfloat16_as_ushort(__float2bfloat16(x));
}
__device__ __forceinline__ float bf2f(ush h){
  return __bfloat162float(__ushort_as_bfloat16(h));
}
__device__ __forceinline__ unsigned int pk2(float a, float b){
  return (unsigned int)f2bf(a) | ((unsigned int)f2bf(b) << 16);
}

// ---- fused weight convert: W (K x N) fp32 -> Wt (N x K) bf16 hi (+lo for z<2)
__global__ void wconv4(const float* __restrict__ W0, const float* __restrict__ W1,
                       const float* __restrict__ W2, const float* __restrict__ W3,
                       ush* __restrict__ H0, ush* __restrict__ H1,
                       ush* __restrict__ H2, ush* __restrict__ H3,
                       ush* __restrict__ L0, ush* __restrict__ L1)
{
  __shared__ float T[32][33];
  const int tx = threadIdx.x, ty = threadIdx.y;    // (32,8)
  const int z = blockIdx.z;
  const float* W = (z==0)?W0:(z==1)?W1:(z==2)?W2:W3;
  ush* H = (z==0)?H0:(z==1)?H1:(z==2)?H2:H3;
  ush* L = (z==0)?L0:(z==1)?L1:nullptr;
  const int k0 = blockIdx.y*32, n0 = blockIdx.x*32;
  #pragma unroll
  for (int i = 0; i < 4; ++i){
    int r = ty + 8*i;
    T[r][tx] = W[(size_t)(k0 + r)*DM + n0 + tx];
  }
  __syncthreads();
  #pragma unroll
  for (int i = 0; i < 4; ++i){
    int r = ty + 8*i;              // n-local
    float v = T[tx][r];
    ush hh = f2bf(v);
    H[(size_t)(n0 + r)*DM + k0 + tx] = hh;
    if (z < 2) L[(size_t)(n0 + r)*DM + k0 + tx] = f2bf(v - bf2f(hh));
  }
}

// ---- MFMA GEMM: C = A(4096x1024) @ Wt^T + bias, Wt stored (N,K) bf16.
// AMODE 0: A fp32 -> bf16 hi; 2-term with B hi/lo (xh*wh + xh*wl)
// AMODE 1: A fp32 -> plain bf16, B hi only
// AMODE 2: A already bf16, B hi only
// OUTMODE 0: fp32 (M,N)+bias; 1: split bf16 (b*16+h,s,dk); 2: bf16 (b*16+h,dk,s)
template<int AMODE, int OUTMODE>
__global__ __launch_bounds__(256) void gemm_mfma(
    const float* __restrict__ Af, const ush* __restrict__ Abf,
    const ush* __restrict__ Bth, const ush* __restrict__ Btl,
    const float* __restrict__ bias,
    float* __restrict__ outf, ush* __restrict__ outh, ush* __restrict__ outl)
{
  constexpr int LDT = 40;
  constexpr bool SPLITB = (AMODE == 0);
  extern __shared__ ush sm[];
  ush* As_h = sm;
  ush* Bs_h = sm + 128*LDT;
  ush* Bs_l = sm + 2*128*LDT;

  const int tid = threadIdx.x;
  const int lane = tid & 63, w = tid >> 6;
  const int c = lane & 15, g = lane >> 4;
  const int wr = w >> 1, wc = w & 1;
  const int m0 = blockIdx.y * 128, n0 = blockIdx.x * 128;

  f32x4 acc[4][4];
  #pragma unroll
  for (int i = 0; i < 4; ++i)
    #pragma unroll
    for (int j = 0; j < 4; ++j) acc[i][j] = (f32x4){0.f,0.f,0.f,0.f};

  const int sr = tid >> 1;
  const int sk = (tid & 1) * 16;

  for (int kt = 0; kt < DM; kt += 32){
    __syncthreads();
    // stage A (hi only)
    if (AMODE == 2){
      const ush* ap = Abf + (size_t)(m0 + sr)*DM + kt + sk;
      *(uint4*)&As_h[sr*LDT + sk]     = *(const uint4*)(ap);
      *(uint4*)&As_h[sr*LDT + sk + 8] = *(const uint4*)(ap + 8);
    } else {
      const float* ap = Af + (size_t)(m0 + sr)*DM + kt + sk;
      float av[16];
      *(float4*)&av[0]  = *(const float4*)(ap);
      *(float4*)&av[4]  = *(const float4*)(ap + 4);
      *(float4*)&av[8]  = *(const float4*)(ap + 8);
      *(float4*)&av[12] = *(const float4*)(ap + 12);
      unsigned int hu[8];
      #pragma unroll
      for (int p = 0; p < 8; ++p) hu[p] = pk2(av[2*p], av[2*p+1]);
      *(uint4*)&As_h[sr*LDT + sk]     = *(const uint4*)&hu[0];
      *(uint4*)&As_h[sr*LDT + sk + 8] = *(const uint4*)&hu[4];
    }
    // stage B
    {
      const ush* bp = Bth + (size_t)(n0 + sr)*DM + kt + sk;
      *(uint4*)&Bs_h[sr*LDT + sk]     = *(const uint4*)(bp);
      *(uint4*)&Bs_h[sr*LDT + sk + 8] = *(const uint4*)(bp + 8);
      if (SPLITB){
        const ush* blp = Btl + (size_t)(n0 + sr)*DM + kt + sk;
        *(uint4*)&Bs_l[sr*LDT + sk]     = *(const uint4*)(blp);
        *(uint4*)&Bs_l[sr*LDT + sk + 8] = *(const uint4*)(blp + 8);
      }
    }
    __syncthreads();

    bf8_t a_h[4];
    #pragma unroll
    for (int fm = 0; fm < 4; ++fm)
      a_h[fm] = *(const bf8_t*)&As_h[(64*wr + 16*fm + c)*LDT + 8*g];
    #pragma unroll
    for (int fn = 0; fn < 4; ++fn){
      bf8_t b_h = *(const bf8_t*)&Bs_h[(64*wc + 16*fn + c)*LDT + 8*g];
      #pragma unroll
      for (int fm = 0; fm < 4; ++fm)
        acc[fm][fn] = MFMA16(a_h[fm], b_h, acc[fm][fn]);
      if (SPLITB){
        bf8_t b_l = *(const bf8_t*)&Bs_l[(64*wc + 16*fn + c)*LDT + 8*g];
        #pragma unroll
        for (int fm = 0; fm < 4; ++fm)
          acc[fm][fn] = MFMA16(a_h[fm], b_l, acc[fm][fn]);
      }
    }
  }

  // epilogue (C/D: col = lane&15, row = 4*(lane>>4)+reg)
  #pragma unroll
  for (int fm = 0; fm < 4; ++fm){
    #pragma unroll
    for (int fn = 0; fn < 4; ++fn){
      const int col = n0 + 64*wc + 16*fn + c;
      const float bb = bias[col];
      const int row0 = m0 + 64*wr + 16*fm + 4*g;
      if (OUTMODE == 0){
        #pragma unroll
        for (int r = 0; r < 4; ++r)
          outf[(size_t)(row0 + r)*DM + col] = acc[fm][fn][r] + bb;
      } else if (OUTMODE == 1){
        const int hd = col >> 6, d = col & 63;
        #pragma unroll
        for (int r = 0; r < 4; ++r){
          const int row = row0 + r;
          const int b = row >> 10, s = row & 1023;
          const size_t a = ((size_t)(b*NH + hd)*SS + s)*DKH + d;
          float v = acc[fm][fn][r] + bb;
          ush hh = f2bf(v);
          outh[a] = hh;
          outl[a] = f2bf(v - bf2f(hh));
        }
      } else {
        const int hd = col >> 6, d = col & 63;
        const int b = row0 >> 10, s = row0 & 1023;
        const size_t a = ((size_t)(b*NH + hd)*DKH + d)*SS + s;
        uint2 pk;
        pk.x = pk2(acc[fm][fn][0] + bb, acc[fm][fn][1] + bb);
        pk.y = pk2(acc[fm][fn][2] + bb, acc[fm][fn][3] + bb);
        *(uint2*)&outh[a] = pk;
      }
    }
  }
}

// ---- Stats pass (swapped QK^T: lane-local q-rows, no max-subtraction)
__global__ __launch_bounds__(256) void attn_stats_mfma(
    const ush* __restrict__ Qh, const ush* __restrict__ Ql,
    const ush* __restrict__ Kh, float* __restrict__ stats)
{
  __shared__ ush Khs[64*72];
  __shared__ float red[4][3];
  const int tid = threadIdx.x, lane = tid & 63, w = tid >> 6;
  const int c = lane & 15, g = lane >> 4;
  const int bh = blockIdx.y, q0 = blockIdx.x * 64;

  bf8_t qh[2], ql[2];
  {
    const size_t qoff = ((size_t)bh*SS + q0 + 16*w + c)*DKH + 8*g;
    qh[0] = *(const bf8_t*)(Qh + qoff);  qh[1] = *(const bf8_t*)(Qh + qoff + 32);
    ql[0] = *(const bf8_t*)(Ql + qoff);  ql[1] = *(const bf8_t*)(Ql + qoff + 32);
  }

  float ssum = 0.f, rmax = -1e30f, lsum = 0.f, l2sum = 0.f;
  const int strow = tid >> 3, stch = (tid & 7) * 8;

  for (int kc = 0; kc < 16; ++kc){
    __syncthreads();
    #pragma unroll
    for (int rep = 0; rep < 2; ++rep){
      int rr = strow + 32*rep;
      *(uint4*)&Khs[rr*72 + stch] =
        *(const uint4*)(Kh + ((size_t)bh*SS + kc*64 + rr)*DKH + stch);
    }
    __syncthreads();

    f32x4 sa[4];
    #pragma unroll
    for (int fn = 0; fn < 4; ++fn) sa[fn] = (f32x4){0.f,0.f,0.f,0.f};
    #pragma unroll
    for (int fn = 0; fn < 4; ++fn){
      #pragma unroll
      for (int ds = 0; ds < 2; ++ds){
        bf8_t ah = *(const bf8_t*)&Khs[(16*fn + c)*72 + 8*g + 32*ds];
        sa[fn] = MFMA16(ah, qh[ds], sa[fn]);   // 2-term: q_hi + q_lo vs K_hi
        sa[fn] = MFMA16(ah, ql[ds], sa[fn]);
      }
    }
    #pragma unroll
    for (int fn = 0; fn < 4; ++fn){
      #pragma unroll
      for (int r = 0; r < 4; ++r){
        float s = sa[fn][r] * 0.125f;
        s = fminf(fmaxf(s, -50.f), 50.f);
        ssum += s;
        rmax = fmaxf(rmax, s);
        float e = exp2f(s * 0.7213475204f);    // exp(s/2), clip bounds keep fp32 safe
        lsum += e;
        l2sum = fmaf(e, e, l2sum);
      }
    }
  }

  // combine 4 g-lanes (same q-row c)
  rmax  = fmaxf(rmax, __shfl_xor(rmax, 16, 64));
  rmax  = fmaxf(rmax, __shfl_xor(rmax, 32, 64));
  lsum  += __shfl_xor(lsum, 16, 64);   lsum  += __shfl_xor(lsum, 32, 64);
  l2sum += __shfl_xor(l2sum, 16, 64);  l2sum += __shfl_xor(l2sum, 32, 64);
  float varc = (l2sum/(lsum*lsum) - (1.0f/1024.f)) * (1.0f/1023.f);
  float a0 = ssum, a1 = rmax * 0.25f, a2 = varc * 0.25f;  // /4 for g-duplication
  #pragma unroll
  for (int off = 1; off < 64; off <<= 1){
    a0 += __shfl_xor(a0, off, 64);
    a1 += __shfl_xor(a1, off, 64);
    a2 += __shfl_xor(a2, off, 64);
  }
  if (lane == 0){ red[w][0] = a0; red[w][1] = a1; red[w][2] = a2; }
  __syncthreads();
  if (tid == 0){
    atomicAdd(&stats[bh*4+0], red[0][0]+red[1][0]+red[2][0]+red[3][0]);
    atomicAdd(&stats[bh*4+1], red[0][1]+red[1][1]+red[2][1]+red[3][1]);
    atomicAdd(&stats[bh*4+2], red[0][2]+red[1][2]+red[2][2]+red[3][2]);
  }
}

__global__ void time_mlp(const float* __restrict__ stats,
    const float* __restrict__ Wt1, const float* __restrict__ bt1,
    const float* __restrict__ Wt2, const float* __restrict__ bt2,
    float* __restrict__ tws)
{
  int bh = threadIdx.x;
  if (bh >= NBH) return;
  float mean = stats[bh*4+0] * (1.f/(1024.f*1024.f));
  float mx   = stats[bh*4+1] * (1.f/1024.f);
  float ent  = stats[bh*4+2] * (1.f/1024.f);
  mean = fminf(fmaxf(mean, -10.f), 10.f);
  mx   = fminf(fmaxf(mx,   -10.f), 10.f);
  ent  = fminf(fmaxf(ent,    0.f),  1.f);
  float raw = bt2[0];
  #pragma unroll
  for (int j = 0; j < 16; ++j){
    float h = tanhf(mean*Wt1[j] + mx*Wt1[16+j] + ent*Wt1[32+j] + bt1[j]);
    raw += h * Wt2[j];
  }
  float sig = 1.f / (1.f + expf(-raw));
  float t = 0.01f + sig * 1.99f;
  t = fminf(fmaxf(t, 0.01f), 2.0f);
  t = fminf(t, 0.85f);
  tws[bh] = t;
}

// ---- Flash pass (swapped QK^T, exp2 domain, defer-max, PV via MFMA)
__global__ __launch_bounds__(256) void attn_flash_mfma(
    const ush* __restrict__ Qh, const ush* __restrict__ Ql,
    const ush* __restrict__ Kh, const ush* __restrict__ Kl,
    const ush* __restrict__ Vt, const float* __restrict__ tws,
    ush* __restrict__ aout)
{
  __shared__ ush Khs[64*72], Kls[64*72], Vts[64*72], Ps[64*72];
  __shared__ float Ls[4][16];
  const int tid = threadIdx.x, lane = tid & 63, w = tid >> 6;
  const int c = lane & 15, g = lane >> 4;
  const int bh = blockIdx.y, q0 = blockIdx.x * 64;
  const float tsc2 = (0.5f / tws[bh]) * 1.44269504f;   // exp2 domain

  bf8_t qh[2], ql[2];
  {
    const size_t qoff = ((size_t)bh*SS + q0 + 16*w + c)*DKH + 8*g;
    qh[0] = *(const bf8_t*)(Qh + qoff);  qh[1] = *(const bf8_t*)(Qh + qoff + 32);
    ql[0] = *(const bf8_t*)(Ql + qoff);  ql[1] = *(const bf8_t*)(Ql + qoff + 32);
  }

  f32x4 o[4];
  #pragma unroll
  for (int i = 0; i < 4; ++i) o[i] = (f32x4){0.f,0.f,0.f,0.f};
  float m = -INFINITY, l = 0.f;

  const int strow = tid >> 3, stch = (tid & 7) * 8;

  for (int kc = 0; kc < 16; ++kc){
    __syncthreads();
    #pragma unroll
    for (int rep = 0; rep < 2; ++rep){
      int rr = strow + 32*rep;
      const size_t gk = ((size_t)bh*SS + kc*64 + rr)*DKH + stch;
      *(uint4*)&Khs[rr*72 + stch] = *(const uint4*)(Kh + gk);
      *(uint4*)&Kls[rr*72 + stch] = *(const uint4*)(Kl + gk);
      *(uint4*)&Vts[rr*72 + stch] =
        *(const uint4*)(Vt + ((size_t)bh*DKH + rr)*SS + kc*64 + stch);
    }
    __syncthreads();

    f32x4 sa[4];
    #pragma unroll
    for (int fn = 0; fn < 4; ++fn) sa[fn] = (f32x4){0.f,0.f,0.f,0.f};
    #pragma unroll
    for (int fn = 0; fn < 4; ++fn){
      #pragma unroll
      for (int ds = 0; ds < 2; ++ds){
        bf8_t ah = *(const bf8_t*)&Khs[(16*fn + c)*72 + 8*g + 32*ds];
        bf8_t al = *(const bf8_t*)&Kls[(16*fn + c)*72 + 8*g + 32*ds];
        sa[fn] = MFMA16(ah, qh[ds], sa[fn]);   // 3-term split
        sa[fn] = MFMA16(al, qh[ds], sa[fn]);
        sa[fn] = MFMA16(ah, ql[ds], sa[fn]);
      }
    }

    // lane-local softmax for q = q0+16w+c over this tile's 64 kv (split over g)
    float x[4][4];
    float pmax = -1e30f;
    #pragma unroll
    for (int fn = 0; fn < 4; ++fn)
      #pragma unroll
      for (int r = 0; r < 4; ++r){
        x[fn][r] = sa[fn][r] * tsc2;
        pmax = fmaxf(pmax, x[fn][r]);
      }
    pmax = fmaxf(pmax, __shfl_xor(pmax, 16, 64));
    pmax = fmaxf(pmax, __shfl_xor(pmax, 32, 64));

    if (!__all(pmax <= m + 30.f)){       // defer-max: fires ~once (kc=0)
      float mn = fmaxf(m, pmax);
      float sc = exp2f(m - mn);
      m = mn;
      l *= sc;
      Ls[w][c] = sc;                     // redistribute scale to o's row indexing
      #pragma unroll
      for (int r = 0; r < 4; ++r){
        float so = Ls[w][4*g + r];
        #pragma unroll
        for (int fn = 0; fn < 4; ++fn) o[fn][r] *= so;
      }
    }

    float lsum = 0.f;
    #pragma unroll
    for (int fn = 0; fn < 4; ++fn){
      float e0 = exp2f(x[fn][0] - m);
      float e1 = exp2f(x[fn][1] - m);
      float e2 = exp2f(x[fn][2] - m);
      float e3 = exp2f(x[fn][3] - m);
      lsum += (e0 + e1) + (e2 + e3);
      uint2 pk;
      pk.x = pk2(e0, e1);
      pk.y = pk2(e2, e3);
      *(uint2*)&Ps[(16*w + c)*72 + 16*fn + 4*g] = pk;   // P[q-local][kv]
    }
    lsum += __shfl_xor(lsum, 16, 64);
    lsum += __shfl_xor(lsum, 32, 64);
    l += lsum;

    // PV: A = P rows (wave-local), B = V^T tile
    #pragma unroll
    for (int kvs = 0; kvs < 2; ++kvs){
      bf8_t pa = *(const bf8_t*)&Ps[(16*w + c)*72 + 8*g + 32*kvs];
      #pragma unroll
      for (int fn = 0; fn < 4; ++fn){
        bf8_t vb = *(const bf8_t*)&Vts[(16*fn + c)*72 + 8*g + 32*kvs];
        o[fn] = MFMA16(pa, vb, o[fn]);
      }
    }
  }

  Ls[w][c] = l;                          // wave-local l broadcast
  const int b = bh >> 4, hd = bh & 15;
  #pragma unroll
  for (int r = 0; r < 4; ++r){
    float linv = 1.f / Ls[w][4*g + r];
    const int q = q0 + 16*w + 4*g + r;
    #pragma unroll
    for (int fn = 0; fn < 4; ++fn)
      aout[((size_t)(b*SS + q))*DM + hd*DKH + 16*fn + c] = f2bf(o[fn][r] * linv);
  }
}

extern "C" void kernel_launch(void* const* d_in, const int* in_sizes, int n_in,
                              void* d_out, int out_size, void* d_ws, size_t ws_size,
                              hipStream_t stream)
{
  const float* query = (const float*)d_in[0];
  const float* key   = (const float*)d_in[1];
  const float* value = (const float*)d_in[2];
  const float* Wq = (const float*)d_in[3];
  const float* bq = (const float*)d_in[4];
  const float* Wk = (const float*)d_in[5];
  const float* bk = (const float*)d_in[6];
  const float* Wv = (const float*)d_in[7];
  const float* bv = (const float*)d_in[8];
  const float* Wo = (const float*)d_in[9];
  const float* bo = (const float*)d_in[10];
  const float* Wt1 = (const float*)d_in[11];
  const float* bt1 = (const float*)d_in[12];
  const float* Wt2 = (const float*)d_in[13];
  const float* bt2 = (const float*)d_in[14];

  ush* ws16 = (ush*)d_ws;
  const size_t E = (size_t)NB*SS*DM;
  const size_t WE = (size_t)DM*DM;
  ush* Qhb = ws16;
  ush* Qlb = Qhb + E;
  ush* Khb = Qlb + E;
  ush* Klb = Khb + E;
  ush* Vtb = Klb + E;
  ush* Aob = Vtb + E;
  ush* Wqh = Aob + E;
  ush* Wql = Wqh + WE;
  ush* Wkh = Wql + WE;
  ush* Wkl = Wkh + WE;
  ush* Wvh = Wkl + WE;
  ush* Woh = Wvh + WE;
  float* stats = (float*)(Woh + WE);
  float* tws   = stats + 4*NBH;

  hipMemsetAsync(stats, 0, 4*NBH*sizeof(float), stream);

  dim3 wb(32, 8), wg(32, 32, 4);
  wconv4<<<wg, wb, 0, stream>>>(Wq, Wk, Wv, Wo, Wqh, Wkh, Wvh, Woh, Wql, Wkl);

  dim3 gg(DM/128, (NB*SS)/128);
  const size_t shm_split = 3u*128*40*2;    // 30720 B
  const size_t shm_plain = 2u*128*40*2;    // 20480 B
  gemm_mfma<0,1><<<gg, 256, shm_split, stream>>>(query, nullptr, Wqh, Wql, bq, nullptr, Qhb, Qlb);
  gemm_mfma<0,1><<<gg, 256, shm_split, stream>>>(key,   nullptr, Wkh, Wkl, bk, nullptr, Khb, Klb);
  gemm_mfma<1,2><<<gg, 256, shm_plain, stream>>>(value, nullptr, Wvh, nullptr, bv, nullptr, Vtb, nullptr);

  dim3 ga(SS/64, NBH);
  attn_stats_mfma<<<ga, 256, 0, stream>>>(Qhb, Qlb, Khb, stats);
  time_mlp<<<1, 64, 0, stream>>>(stats, Wt1, bt1, Wt2, bt2, tws);
  attn_flash_mfma<<<ga, 256, 0, stream>>>(Qhb, Qlb, Khb, Klb, Vtb, tws, Aob);

  gemm_mfma<2,0><<<gg, 256, shm_plain, stream>>>(nullptr, Aob, Woh, nullptr, bo, (float*)d_out, nullptr, nullptr);
}